// Round 5
// baseline (4985.073 us; speedup 1.0000x reference)
//
#include <hip/hip_runtime.h>
#include <math.h>

#define NN 50000
#define NE 800000
#define NGRAPH 100
#define NPG 500
#define NB_SCAN 196            // ceil(NN/256)
#define SLICE_ELEMS ((size_t)NN * 16)      // elements per 16-col slice
#define CHAIN_ELEMS ((size_t)4 * NN * 16)  // 4 slices = one 64-col chain buffer
#define GRID_STEP (4 * (NN / 16))          // 4 slices x 3125 node-blocks = 12500

// ---------------- helpers ----------------

__device__ __forceinline__ void ldedge(const int2* p, int& r, float& w) {
    long long v = __builtin_nontemporal_load((const long long*)p);
    r = (int)(v & 0xffffffffLL);
    w = __int_as_float((int)(v >> 32));
}

// ---------------- setup kernels ----------------

__global__ void k_deg(const int* __restrict__ col, int* __restrict__ degi) {
    int e = blockIdx.x * blockDim.x + threadIdx.x;
    if (e < NE) atomicAdd(&degi[col[e]], 1);
}

__global__ void k_dh(const int* __restrict__ degi, float* __restrict__ dh) {
    int i = blockIdx.x * blockDim.x + threadIdx.x;
    if (i < NN) {
        int d = degi[i];
        dh[i] = d > 0 ? (float)(1.0 / sqrt((double)d)) : 0.0f;
    }
}

__global__ void k_bsum(const int* __restrict__ degi, int* __restrict__ bsum) {
    __shared__ int sh[256];
    int i = blockIdx.x * 256 + threadIdx.x;
    sh[threadIdx.x] = (i < NN) ? degi[i] : 0;
    __syncthreads();
    for (int s = 128; s > 0; s >>= 1) {
        if (threadIdx.x < s) sh[threadIdx.x] += sh[threadIdx.x + s];
        __syncthreads();
    }
    if (threadIdx.x == 0) bsum[blockIdx.x] = sh[0];
}

__global__ void k_bscan(const int* __restrict__ bsum, int* __restrict__ boff) {
    __shared__ int sh[2][256];
    int v = (threadIdx.x < NB_SCAN) ? bsum[threadIdx.x] : 0;
    int cur = 0;
    sh[0][threadIdx.x] = v;
    __syncthreads();
    for (int s = 1; s < 256; s <<= 1) {
        int val = sh[cur][threadIdx.x];
        if ((int)threadIdx.x >= s) val += sh[cur][threadIdx.x - s];
        sh[cur ^ 1][threadIdx.x] = val;
        cur ^= 1;
        __syncthreads();
    }
    if (threadIdx.x < NB_SCAN) boff[threadIdx.x] = sh[cur][threadIdx.x] - v;
}

__global__ void k_scan2(const int* __restrict__ degi, const int* __restrict__ boff,
                        int* __restrict__ off) {
    __shared__ int sh[2][256];
    int i = blockIdx.x * 256 + threadIdx.x;
    int v = (i < NN) ? degi[i] : 0;
    int cur = 0;
    sh[0][threadIdx.x] = v;
    __syncthreads();
    for (int s = 1; s < 256; s <<= 1) {
        int val = sh[cur][threadIdx.x];
        if ((int)threadIdx.x >= s) val += sh[cur][threadIdx.x - s];
        sh[cur ^ 1][threadIdx.x] = val;
        cur ^= 1;
        __syncthreads();
    }
    if (i < NN) off[i] = boff[blockIdx.x] + sh[cur][threadIdx.x] - v;
}

__global__ void k_fill(const int* __restrict__ row, const int* __restrict__ col,
                       const float* __restrict__ dh, const int* __restrict__ off,
                       int* __restrict__ cursor, int2* __restrict__ csrp) {
    int e = blockIdx.x * blockDim.x + threadIdx.x;
    if (e >= NE) return;
    int r = row[e], c = col[e];
    int pos = off[c] + atomicAdd(&cursor[c], 1);
    csrp[pos] = make_int2(r, __float_as_int(dh[r] * dh[c]));
}

// ---------------- recurrence kernels (fp32, 16-col slices) ----------------
// block = 256 threads = 16 nodes x 16 lanes; slice q = blockIdx & 3.
// Sliced buffers: element (q, node, f) at q*SLICE_ELEMS + node*16 + f.

// T1 = -A.src ; src in arbitrary layout: src[q*sSlice + r*sRow + f]
__global__ __launch_bounds__(256) void k_init(
    const float* __restrict__ src, int sSlice, int sRow,
    const int* __restrict__ off, const int* __restrict__ degi,
    const int2* __restrict__ csrp, float* __restrict__ Tout) {
    int q = blockIdx.x & 3;
    int node = (blockIdx.x >> 2) * 16 + (threadIdx.x >> 4);
    int f = threadIdx.x & 15;
    const float* sb = src + (size_t)q * sSlice + f;
    int s = off[node], e = s + degi[node];
    float g0 = 0.f, g1 = 0.f;
    int i = s;
    for (; i + 7 < e; i += 8) {
        int r0, r1, r2, r3, r4, r5, r6, r7;
        float w0, w1, w2, w3, w4, w5, w6, w7;
        ldedge(csrp + i, r0, w0);     ldedge(csrp + i + 1, r1, w1);
        ldedge(csrp + i + 2, r2, w2); ldedge(csrp + i + 3, r3, w3);
        ldedge(csrp + i + 4, r4, w4); ldedge(csrp + i + 5, r5, w5);
        ldedge(csrp + i + 6, r6, w6); ldedge(csrp + i + 7, r7, w7);
        g0 += w0 * sb[(size_t)r0 * sRow] + w1 * sb[(size_t)r1 * sRow]
            + w2 * sb[(size_t)r2 * sRow] + w3 * sb[(size_t)r3 * sRow];
        g1 += w4 * sb[(size_t)r4 * sRow] + w5 * sb[(size_t)r5 * sRow]
            + w6 * sb[(size_t)r6 * sRow] + w7 * sb[(size_t)r7 * sRow];
    }
    for (; i < e; ++i) {
        int r; float w; ldedge(csrp + i, r, w);
        g0 += w * sb[(size_t)r * sRow];
    }
    __builtin_nontemporal_store(-(g0 + g1),
        &Tout[(size_t)q * SLICE_ELEMS + node * 16 + f]);
}

// Tnext = -2.A.Tcur - Tprev ; Tcur sliced; Tprev arbitrary layout
__global__ __launch_bounds__(256) void k_step(
    const float* __restrict__ Tcur, const float* __restrict__ Tprev,
    int pSlice, int pRow, float* __restrict__ Tnext,
    const int* __restrict__ off, const int* __restrict__ degi,
    const int2* __restrict__ csrp) {
    int q = blockIdx.x & 3;
    int node = (blockIdx.x >> 2) * 16 + (threadIdx.x >> 4);
    int f = threadIdx.x & 15;
    const float* cb = Tcur + (size_t)q * SLICE_ELEMS + f;
    int s = off[node], e = s + degi[node];
    float g0 = 0.f, g1 = 0.f;
    int i = s;
    for (; i + 7 < e; i += 8) {
        int r0, r1, r2, r3, r4, r5, r6, r7;
        float w0, w1, w2, w3, w4, w5, w6, w7;
        ldedge(csrp + i, r0, w0);     ldedge(csrp + i + 1, r1, w1);
        ldedge(csrp + i + 2, r2, w2); ldedge(csrp + i + 3, r3, w3);
        ldedge(csrp + i + 4, r4, w4); ldedge(csrp + i + 5, r5, w5);
        ldedge(csrp + i + 6, r6, w6); ldedge(csrp + i + 7, r7, w7);
        g0 += w0 * cb[r0 * 16] + w1 * cb[r1 * 16]
            + w2 * cb[r2 * 16] + w3 * cb[r3 * 16];
        g1 += w4 * cb[r4 * 16] + w5 * cb[r5 * 16]
            + w6 * cb[r6 * 16] + w7 * cb[r7 * 16];
    }
    for (; i < e; ++i) {
        int r; float w; ldedge(csrp + i, r, w);
        g0 += w * cb[r * 16];
    }
    float pv = __builtin_nontemporal_load(
        &Tprev[(size_t)q * pSlice + (size_t)node * pRow + f]);
    __builtin_nontemporal_store(-2.f * (g0 + g1) - pv,
        &Tnext[(size_t)q * SLICE_ELEMS + node * 16 + f]);
}

// ---------------- combine: acc planes from 4 pool slots ----------------
// pool: 4 slots, each CHAIN_ELEMS (sliced). accb planes sliced: plane*CHAIN_ELEMS + idx.

struct CombCfg {
    float c0[4];
    float ck[4][4];
    int   plane[4];
};

template <int NT, bool FIRST, bool ABS>
__global__ __launch_bounds__(256) void k_combine(
    const float* __restrict__ src0, int s0Slice, int s0Row,
    const float* __restrict__ pool, float* __restrict__ accb, CombCfg cfg) {
    int q = blockIdx.x & 3;
    int node = (blockIdx.x >> 2) * 16 + (threadIdx.x >> 4);
    int f = threadIdx.x & 15;
    size_t idx = (size_t)q * SLICE_ELEMS + node * 16 + f;
    float tv[4];
#pragma unroll
    for (int m = 0; m < 4; ++m)
        tv[m] = __builtin_nontemporal_load(&pool[(size_t)m * CHAIN_ELEMS + idx]);
    float s0 = FIRST
        ? __builtin_nontemporal_load(&src0[(size_t)q * s0Slice + (size_t)node * s0Row + f])
        : 0.f;
#pragma unroll
    for (int t = 0; t < NT; ++t) {
        size_t o = (size_t)cfg.plane[t] * CHAIN_ELEMS + idx;
        float a = FIRST ? cfg.c0[t] * s0 : __builtin_nontemporal_load(&accb[o]);
#pragma unroll
        for (int m = 0; m < 4; ++m) a += cfg.ck[t][m] * tv[m];
        if (ABS) a = fabsf(a);
        __builtin_nontemporal_store(a, &accb[o]);
    }
}

// ---------------- moments ----------------
// cols: [0,64)->x [NN,64]; [64,320)->hacc sliced planes; [320,704)->acc2 sliced planes
__global__ void k_moments(const float* __restrict__ x, const float* __restrict__ hacc,
                          const float* __restrict__ acc2, float* __restrict__ out) {
    int g = blockIdx.y;
    int col = blockIdx.x * 256 + threadIdx.x;
    if (col >= 704) return;
    const float* src;
    size_t stride;  // per-node stride
    size_t base0;
    if (col < 64) {
        src = x; stride = 64; base0 = col;
    } else if (col < 320) {
        int cp = col - 64, pl = cp >> 6, cc = cp & 63, q = cc >> 4, f = cc & 15;
        src = hacc; stride = 16;
        base0 = (size_t)pl * CHAIN_ELEMS + (size_t)q * SLICE_ELEMS + f;
    } else {
        int cp = col - 320, pl = cp >> 6, cc = cp & 63, q = cc >> 4, f = cc & 15;
        src = acc2; stride = 16;
        base0 = (size_t)pl * CHAIN_ELEMS + (size_t)q * SLICE_ELEMS + f;
    }
    double s1 = 0, s2 = 0, s3 = 0, s4 = 0;
    int base = g * NPG;
    for (int i = 0; i < NPG; ++i) {
        double v = (double)src[base0 + (size_t)(base + i) * stride];
        double v2 = v * v;
        s1 += v; s2 += v2; s3 += v2 * v; s4 += v2 * v2;
    }
    double n = (double)NPG;
    double mu = s1 / n;
    double E2 = s2 / n, E3 = s3 / n, E4 = s4 / n;
    double m2 = E2 - mu * mu;
    double m3 = E3 - 3.0 * mu * E2 + 2.0 * mu * mu * mu;
    double m4 = E4 - 4.0 * mu * E3 + 6.0 * mu * mu * E2 - 3.0 * mu * mu * mu * mu;
    float m2f = (float)m2;
    float skew = 0.f, kurt = -3.f;
    if (m2f > 0.f) {
        skew = (float)(m3 / (m2 * sqrt(m2)));
        if (skew > 1e15f) skew = 0.f;
        kurt = (float)(m4 / (m2 * m2) - 3.0);
        if (kurt > 1e15f) kurt = -3.f;
    }
    size_t ob = (size_t)g * 2816 + col;
    out[ob]        = (float)mu;
    out[ob + 704]  = m2f;
    out[ob + 1408] = skew;
    out[ob + 2112] = kurt;
}

// ---------------- host ----------------

extern "C" void kernel_launch(void* const* d_in, const int* in_sizes, int n_in,
                              void* d_out, int out_size, void* d_ws, size_t ws_size,
                              hipStream_t stream) {
    const float* x = (const float*)d_in[0];
    const int* ei  = (const int*)d_in[1];
    const int* row = ei;
    const int* col = ei + NE;
    float* out = (float*)d_out;

    // Chebyshev coefficients [17][4], double precision (matches numpy)
    float C[17][4];
    {
        const int Nc = 17;
        const int scales[4] = {2, 4, 8, 16};
        for (int si = 0; si < 4; ++si) {
            double ker[17];
            for (int j = 0; j < Nc; ++j) {
                double num = cos(M_PI * (j + 0.5) / Nc);
                double b = -num;
                double v = pow(b, (double)(scales[si] / 2)) - pow(b, (double)scales[si]);
                if (v < 0) v = 0;
                ker[j] = sqrt(v);
            }
            for (int o = 0; o < Nc; ++o) {
                double acc = 0;
                for (int j = 0; j < Nc; ++j) acc += ker[j] * cos(M_PI * o * (j + 0.5) / Nc);
                C[o][si] = (float)(2.0 / Nc * acc);
            }
        }
    }

    // workspace carve (~186 MB)
    char* p = (char*)d_ws;
    auto alloc = [&](size_t bytes) -> void* {
        void* r = (void*)p;
        p += (bytes + 255) & ~(size_t)255;
        return r;
    };
    int*   degi   = (int*)alloc((size_t)NN * 4);
    float* dh     = (float*)alloc((size_t)NN * 4);
    int*   off    = (int*)alloc((size_t)NN * 4);
    int*   cursor = (int*)alloc((size_t)NN * 4);
    int*   bsum   = (int*)alloc((size_t)NB_SCAN * 4);
    int*   boff   = (int*)alloc((size_t)NB_SCAN * 4);
    int2*  csrp   = (int2*)alloc((size_t)NE * 8);                // 6.4 MB
    float* pool   = (float*)alloc((size_t)4 * CHAIN_ELEMS * 4);  // 51.2 MB
    float* hacc   = (float*)alloc((size_t)4 * CHAIN_ELEMS * 4);  // 51.2 MB
    float* acc2   = (float*)alloc((size_t)6 * CHAIN_ELEMS * 4);  // 76.8 MB
    if ((size_t)(p - (char*)d_ws) > ws_size) return;

    hipMemsetAsync(degi, 0, (size_t)NN * 4, stream);
    hipMemsetAsync(cursor, 0, (size_t)NN * 4, stream);

    k_deg  <<<(NE + 255) / 256, 256, 0, stream>>>(col, degi);
    k_dh   <<<(NN + 255) / 256, 256, 0, stream>>>(degi, dh);
    k_bsum <<<NB_SCAN, 256, 0, stream>>>(degi, bsum);
    k_bscan<<<1, 256, 0, stream>>>(bsum, boff);
    k_scan2<<<NB_SCAN, 256, 0, stream>>>(degi, boff, off);
    k_fill <<<(NE + 255) / 256, 256, 0, stream>>>(row, col, dh, off, cursor, csrp);

    auto slot = [&](int k) { return pool + (size_t)((k - 1) & 3) * CHAIN_ELEMS; };

    // run one chain: src (layout sSlice/sRow) -> acc planes of accb
    auto run_chain = [&](const float* src, int sSlice, int sRow, float* accb,
                         const int* scl, const int* pln, int nt) {
        k_init<<<GRID_STEP, 256, 0, stream>>>(src, sSlice, sRow, off, degi, csrp, slot(1));
        for (int k = 2; k <= 16; ++k) {
            const float* Tprev = (k == 2) ? src : slot(k - 2);
            int pS = (k == 2) ? sSlice : (int)SLICE_ELEMS;
            int pR = (k == 2) ? sRow : 16;
            k_step<<<GRID_STEP, 256, 0, stream>>>(slot(k - 1), Tprev, pS, pR, slot(k),
                                                  off, degi, csrp);
            if ((k & 3) == 0) {
                CombCfg cfg;
                for (int t = 0; t < nt; ++t) {
                    int si = scl[t];
                    cfg.c0[t] = 0.5f * C[0][si];
                    cfg.plane[t] = pln[t];
                    for (int m = 0; m < 4; ++m) cfg.ck[t][m] = C[k - 3 + m][si];
                }
                bool first = (k == 4), last = (k == 16);
                if (first) {
                    if (nt == 4) k_combine<4, true, false><<<GRID_STEP, 256, 0, stream>>>(src, sSlice, sRow, pool, accb, cfg);
                    if (nt == 3) k_combine<3, true, false><<<GRID_STEP, 256, 0, stream>>>(src, sSlice, sRow, pool, accb, cfg);
                    if (nt == 2) k_combine<2, true, false><<<GRID_STEP, 256, 0, stream>>>(src, sSlice, sRow, pool, accb, cfg);
                    if (nt == 1) k_combine<1, true, false><<<GRID_STEP, 256, 0, stream>>>(src, sSlice, sRow, pool, accb, cfg);
                } else if (last) {
                    if (nt == 4) k_combine<4, false, true><<<GRID_STEP, 256, 0, stream>>>(nullptr, 0, 0, pool, accb, cfg);
                    if (nt == 3) k_combine<3, false, true><<<GRID_STEP, 256, 0, stream>>>(nullptr, 0, 0, pool, accb, cfg);
                    if (nt == 2) k_combine<2, false, true><<<GRID_STEP, 256, 0, stream>>>(nullptr, 0, 0, pool, accb, cfg);
                    if (nt == 1) k_combine<1, false, true><<<GRID_STEP, 256, 0, stream>>>(nullptr, 0, 0, pool, accb, cfg);
                } else {
                    if (nt == 4) k_combine<4, false, false><<<GRID_STEP, 256, 0, stream>>>(nullptr, 0, 0, pool, accb, cfg);
                    if (nt == 3) k_combine<3, false, false><<<GRID_STEP, 256, 0, stream>>>(nullptr, 0, 0, pool, accb, cfg);
                    if (nt == 2) k_combine<2, false, false><<<GRID_STEP, 256, 0, stream>>>(nullptr, 0, 0, pool, accb, cfg);
                    if (nt == 1) k_combine<1, false, false><<<GRID_STEP, 256, 0, stream>>>(nullptr, 0, 0, pool, accb, cfg);
                }
            }
        }
    };

    // ---- phase 1: x [NN,64] -> hacc planes 0..3 (|h| per scale) ----
    {
        const int scl[4] = {0, 1, 2, 3};
        const int pln[4] = {0, 1, 2, 3};
        run_chain(x, 16, 64, hacc, scl, pln, 4);
    }

    // ---- phase 2: 3 chains on hacc planes 0..2 (sliced layout) ----
    {
        const int scl0[3] = {1, 2, 3}; const int pln0[3] = {0, 1, 3};
        run_chain(hacc + 0 * CHAIN_ELEMS, (int)SLICE_ELEMS, 16, acc2, scl0, pln0, 3);
        const int scl1[2] = {2, 3};    const int pln1[2] = {2, 4};
        run_chain(hacc + 1 * CHAIN_ELEMS, (int)SLICE_ELEMS, 16, acc2, scl1, pln1, 2);
        const int scl2[1] = {3};       const int pln2[1] = {5};
        run_chain(hacc + 2 * CHAIN_ELEMS, (int)SLICE_ELEMS, 16, acc2, scl2, pln2, 1);
    }

    // ---- moments ----
    dim3 mg(3, NGRAPH);
    k_moments<<<mg, 256, 0, stream>>>(x, hacc, acc2, out);
}